// Round 14
// baseline (19.571 us; speedup 1.0000x reference)
//
#include <hip/hip_runtime.h>
#include <math.h>

// JPEG layer: RGB->YCbCr, clip/shift, 2x2 chroma pool (sub-OFF after), 8x8 DCT,
// quantize, round. Round-14: WAVE-AUTONOMOUS halves inside 256-thread WGs.
// Each wave owns a 16x32 half-tile: loads+color+pool+DCT fully wave-private,
// ZERO barriers, LDS partitioned per wave. Fixes round-10's confounds (WG-slot
// occupancy cap, 64B segments) while keeping its wave-level de-phasing:
// 16-lane float2 rows = 128B segments; 6 WGs/CU = 24 waves/CU.
// Per wave: 8 Y blocks (round 1, all 64 lanes) + 2 Cb + 2 Cr (round 2, 32 lanes).

static __device__ __forceinline__ float clip01(float v) {
    return fminf(fmaxf(v, 0.0f), 1.0f);
}

// DCT-II 8x8 matrix as compile-time f32 constants: f32(0.5*cos(k*pi/16)).
// Row 0 = 1/sqrt(8), which equals M4 bitwise in f32.
#define M1f 0.49039264020161522f
#define M2f 0.46193976625564337f
#define M3f 0.41573480615127262f
#define M4f 0.35355339059327376f
#define M5f 0.27778511650980111f
#define M6f 0.19134171618254489f
#define M7f 0.097545161008064134f

static constexpr float Dm[8][8] = {
    { M4f,  M4f,  M4f,  M4f,  M4f,  M4f,  M4f,  M4f},
    { M1f,  M3f,  M5f,  M7f, -M7f, -M5f, -M3f, -M1f},
    { M2f,  M6f, -M6f, -M2f, -M2f, -M6f,  M6f,  M2f},
    { M3f, -M7f, -M1f, -M5f,  M5f,  M1f,  M7f, -M3f},
    { M4f, -M4f, -M4f,  M4f,  M4f, -M4f, -M4f,  M4f},
    { M5f, -M1f,  M7f,  M3f, -M3f, -M7f,  M1f, -M5f},
    { M6f, -M2f,  M2f, -M6f, -M6f,  M2f, -M2f,  M6f},
    { M7f, -M5f,  M3f, -M1f,  M1f, -M3f,  M5f, -M7f},
};

__global__ __launch_bounds__(256)
void jpeg_kernel(const float* __restrict__ rgb, const float* __restrict__ quant,
                 float* __restrict__ out)
{
    // LDS partitioned per wave: 1568 dwords each (Yt 640 | Cbt 192 | Crt 192 | TMP 544)
    __shared__ __align__(16) float smem[4 * 1568];
    constexpr int YT  = 0;     // transposed Y half [32 cols][stride 20, rows 0..15]
    constexpr int CBT = 640;   // transposed pooled cb [16 cols][stride 12, rows 0..7]
    constexpr int CRT = 832;   // transposed pooled cr
    constexpr int TMP = 1024;  // 8 blocks * 68

    const int t = threadIdx.x;
    const int w = t >> 6;             // wave 0..3
    const int l = t & 63;
    float* W = smem + w * 1568;       // wave-private LDS

    // wave -> half-tile mapping: WG covers 2 tiles; wave w: tile (w>>1), half (w&1)
    const int tileId = (blockIdx.x << 1) + (w >> 1);   // 0..4095
    const int half   = w & 1;
    const int b  = tileId >> 8;
    const int th = (tileId >> 4) & 15;
    const int tw = tileId & 15;

    const int qc  = l & 15;           // quad col 0..15
    const int qr0 = l >> 4;           // quad row 0..3 (set A); set B = qr0+4
    const int bi  = l >> 3;           // DCT round-1 block 0..7
    const int lc  = l & 7;            // stage-1 col / stage-2 row
    const int bi2 = bi & 3;           // DCT round-2 block 0..3 (lanes <32)
    const int ch2 = 1 + (bi2 >> 1), sc2 = bi2 & 1;

    // ---- issue all global loads first (12 rgb float2 + quant rows) ----
    const int rowbase = th * 32 + half * 16;
    const int colbase = tw * 32;
    const float* pA = rgb + (size_t)b * 786432 + (size_t)(rowbase + 2 * qr0) * 512 + (colbase + 2 * qc);
    const float* pB = pA + 8 * 512;   // quad set B: rows +8
    const float2 AR0 = *(const float2*)pA;
    const float2 AR1 = *(const float2*)(pA + 512);
    const float2 AG0 = *(const float2*)(pA + 262144);
    const float2 AG1 = *(const float2*)(pA + 262656);
    const float2 AB0 = *(const float2*)(pA + 524288);
    const float2 AB1 = *(const float2*)(pA + 524800);
    const float2 BR0 = *(const float2*)pB;
    const float2 BR1 = *(const float2*)(pB + 512);
    const float2 BG0 = *(const float2*)(pB + 262144);
    const float2 BG1 = *(const float2*)(pB + 262656);
    const float2 BB0 = *(const float2*)(pB + 524288);
    const float2 BB1 = *(const float2*)(pB + 524800);
    float q0[8], q2[8];
    *(float4*)&q0[0] = *(const float4*)(quant + lc * 8);
    *(float4*)&q0[4] = *(const float4*)(quant + lc * 8 + 4);
    *(float4*)&q2[0] = *(const float4*)(quant + ch2 * 64 + lc * 8);
    *(float4*)&q2[4] = *(const float4*)(quant + ch2 * 64 + lc * 8 + 4);

    // ---- color transform + in-register pool for both quads ----
    const float OFF = (float)(128.0 / 255.0);
    #pragma unroll
    for (int s = 0; s < 2; ++s) {
        const int qr = qr0 + 4 * s;
        const float2 R0 = s ? BR0 : AR0, R1 = s ? BR1 : AR1;
        const float2 G0 = s ? BG0 : AG0, G1 = s ? BG1 : AG1;
        const float2 B0 = s ? BB0 : AB0, B1 = s ? BB1 : AB1;
        // order: 0=w00, 1=w01, 2=w10, 3=w11
        const float rr[4] = {R0.x, R0.y, R1.x, R1.y};
        const float gg[4] = {G0.x, G0.y, G1.x, G1.y};
        const float bb[4] = {B0.x, B0.y, B1.x, B1.y};
        float yv[4], cbv[4], crv[4];
        #pragma unroll
        for (int k = 0; k < 4; ++k) {
            const float r_ = rr[k], g_ = gg[k], b_ = bb[k];
            const float y  = (float)(0.299) * r_ + (float)(0.587) * g_ + (float)(0.114) * b_;
            const float cb = (float)(-0.168735892) * r_ + (float)(-0.331264108) * g_ + 0.5f * b_;
            const float cr = 0.5f * r_ + (float)(-0.418687589) * g_ + (float)(-0.081312411) * b_;
            yv[k]  = clip01(y) - OFF;
            cbv[k] = clip01(cb + OFF);   // clipped, pre-subtract (subtract after pool)
            crv[k] = clip01(cr + OFF);
        }
        // transposed Y: col c holds Y[r][c] at YT + c*20 + r (local rows 0..15)
        *(float2*)&W[YT + (2 * qc) * 20 + 2 * qr]     = make_float2(yv[0], yv[2]);
        *(float2*)&W[YT + (2 * qc + 1) * 20 + 2 * qr] = make_float2(yv[1], yv[3]);
        // in-register pool, exact reference order ((w00+w01)+w10)+w11, then -OFF
        float sb = cbv[0];
        sb = sb + cbv[1];
        sb = sb + cbv[2];
        sb = sb + cbv[3];
        W[CBT + qc * 12 + qr] = sb * 0.25f - OFF;
        float sr_ = crv[0];
        sr_ = sr_ + crv[1];
        sr_ = sr_ + crv[2];
        sr_ = sr_ + crv[3];
        W[CRT + qc * 12 + qr] = sr_ * 0.25f - OFF;
    }
    // NO barrier anywhere: all consumers below are lanes of the SAME wave;
    // per-wave LDS ops complete in order (mechanism bit-validated rounds 7-13).

    const float qadd = (float)(0.5 / 255.0);

    // ---- DCT round 1: 8 Y blocks, 8 lanes each ----
    {
        const int sr = bi >> 2, sc = bi & 3;
        const int xaddr = YT + (sc * 8 + lc) * 20 + sr * 8;
        float x[8];
        *(float4*)&x[0] = *(const float4*)&W[xaddr];
        *(float4*)&x[4] = *(const float4*)&W[xaddr + 4];
        const int tbase = TMP + bi * 68;
        #pragma unroll
        for (int i = 0; i < 8; ++i) {
            float s = 0.0f;
            #pragma unroll
            for (int j = 0; j < 8; ++j) s += Dm[i][j] * x[j];   // j-ascending
            W[tbase + i * 8 + lc] = s;
        }
        float tr[8];
        *(float4*)&tr[0] = *(const float4*)&W[tbase + lc * 8];
        *(float4*)&tr[4] = *(const float4*)&W[tbase + lc * 8 + 4];
        float o[8];
        #pragma unroll
        for (int cc = 0; cc < 8; ++cc) {
            float s = 0.0f;
            #pragma unroll
            for (int k = 0; k < 8; ++k) s += tr[k] * Dm[cc][k];  // k-ascending
            const float den = __fadd_rn(__fmul_rn(q0[cc], 2.5f), qadd);  // no FMA
            o[cc] = rintf(s / den);   // IEEE div + round-half-even, matches np
        }
        const size_t obase = (((size_t)(b * 64 + th * 4 + half * 2 + sr)) * 64
                              + (tw * 4 + sc)) * 64;
        float* op = out + obase + lc * 8;
        *(float4*)&op[0] = make_float4(o[0], o[1], o[2], o[3]);
        *(float4*)&op[4] = make_float4(o[4], o[5], o[6], o[7]);
    }

    // ---- DCT round 2: 2 Cb + 2 Cr blocks, lanes 0..31 (TMP reuse: same-wave
    //      WAR through the in-order LDS pipe) ----
    if (l < 32) {
        const int xaddr = (ch2 == 1 ? CBT : CRT) + (sc2 * 8 + lc) * 12;
        float x[8];
        *(float4*)&x[0] = *(const float4*)&W[xaddr];
        *(float4*)&x[4] = *(const float4*)&W[xaddr + 4];
        const int tbase = TMP + bi2 * 68;
        #pragma unroll
        for (int i = 0; i < 8; ++i) {
            float s = 0.0f;
            #pragma unroll
            for (int j = 0; j < 8; ++j) s += Dm[i][j] * x[j];
            W[tbase + i * 8 + lc] = s;
        }
        float tr[8];
        *(float4*)&tr[0] = *(const float4*)&W[tbase + lc * 8];
        *(float4*)&tr[4] = *(const float4*)&W[tbase + lc * 8 + 4];
        float o[8];
        #pragma unroll
        for (int cc = 0; cc < 8; ++cc) {
            float s = 0.0f;
            #pragma unroll
            for (int k = 0; k < 8; ++k) s += tr[k] * Dm[cc][k];
            const float den = __fadd_rn(__fmul_rn(q2[cc], 2.5f), qadd);
            o[cc] = rintf(s / den);
        }
        const size_t chbase = (ch2 == 1) ? (size_t)4194304 : (size_t)5242880;
        const size_t obase = chbase + (((size_t)(b * 32 + th * 2 + half)) * 32
                                       + (tw * 2 + sc2)) * 64;
        float* op = out + obase + lc * 8;
        *(float4*)&op[0] = make_float4(o[0], o[1], o[2], o[3]);
        *(float4*)&op[4] = make_float4(o[4], o[5], o[6], o[7]);
    }
}

extern "C" void kernel_launch(void* const* d_in, const int* in_sizes, int n_in,
                              void* d_out, int out_size, void* d_ws, size_t ws_size,
                              hipStream_t stream) {
    const float* rgb   = (const float*)d_in[0];
    const float* quant = (const float*)d_in[1];
    float* out = (float*)d_out;
    dim3 grid(2048), block(256);
    hipLaunchKernelGGL(jpeg_kernel, grid, block, 0, stream, rgb, quant, out);
}

// Round 15
// 18.064 us; speedup vs baseline: 1.0834x; 1.0834x over previous
//
#include <hip/hip_runtime.h>
#include <math.h>

// JPEG layer: RGB->YCbCr, clip/shift, 2x2 chroma pool (sub-OFF after), 8x8 DCT,
// quantize, round. Round-15 = round-9 base (best, 17.97us) + packed-FMA DCT:
// both DCT stages compute output-coefficient PAIRS with v_pk_fma_f32 (via
// __builtin_elementwise_fma on float2 ext-vectors). The two chains in a pair
// are independent; each chain's op sequence (j/k-ascending fma) is unchanged
// -> bit-exact. Color transform deliberately untouched (compiler-chosen
// contraction there is part of the validated bit-exact recipe).

static __device__ __forceinline__ float clip01(float v) {
    return fminf(fmaxf(v, 0.0f), 1.0f);
}

typedef float f32x2 __attribute__((ext_vector_type(2)));

// DCT-II 8x8 matrix as compile-time f32 constants: f32(0.5*cos(k*pi/16)).
// Row 0 = 1/sqrt(8), which equals M4 bitwise in f32.
#define M1f 0.49039264020161522f
#define M2f 0.46193976625564337f
#define M3f 0.41573480615127262f
#define M4f 0.35355339059327376f
#define M5f 0.27778511650980111f
#define M6f 0.19134171618254489f
#define M7f 0.097545161008064134f

static constexpr float Dm[8][8] = {
    { M4f,  M4f,  M4f,  M4f,  M4f,  M4f,  M4f,  M4f},
    { M1f,  M3f,  M5f,  M7f, -M7f, -M5f, -M3f, -M1f},
    { M2f,  M6f, -M6f, -M2f, -M2f, -M6f,  M6f,  M2f},
    { M3f, -M7f, -M1f, -M5f,  M5f,  M1f,  M7f, -M3f},
    { M4f, -M4f, -M4f,  M4f,  M4f, -M4f, -M4f,  M4f},
    { M5f, -M1f,  M7f,  M3f, -M3f, -M7f,  M1f, -M5f},
    { M6f, -M2f,  M2f, -M6f, -M6f,  M2f, -M2f,  M6f},
    { M7f, -M5f,  M3f, -M1f,  M1f, -M3f,  M5f, -M7f},
};

__global__ __launch_bounds__(256)
void jpeg_kernel(const float* __restrict__ rgb, const float* __restrict__ quant,
                 float* __restrict__ out)
{
    // single shared block with integer offsets -> guaranteed ds addressing
    __shared__ __align__(16) float smem[3616];
    constexpr int YTT = 0;     // transposed Y [32 cols][36]
    constexpr int CBT = 1152;  // transposed pooled cb [16 cols][20]
    constexpr int CRT = 1472;  // transposed pooled cr [16 cols][20]
    constexpr int QNT = 1792;  // quant [3][64]
    constexpr int TMP = 1984;  // DCT temp: 4 waves * 6 blocks * 68

    const int t = threadIdx.x;

    // stage quant into LDS (covered by the barrier)
    if (t < 192) smem[QNT + t] = quant[t];

    const int wg   = blockIdx.x;
    const int b    = wg >> 8;         // image index (256 tiles per image)
    const int tile = wg & 255;
    const int th   = tile >> 4;       // tile row 0..15
    const int tw   = tile & 15;       // tile col 0..15

    // ---- color transform + in-register 2x2 pooling: one quad per thread ----
    {
        const int qr = t >> 4;             // quad row 0..15
        const int qc = t & 15;             // quad col 0..15
        const int r0 = 2 * qr, c0 = 2 * qc;
        const float* p = rgb + ((size_t)b * 3) * 262144 + (size_t)(th * 32 + r0) * 512 + (tw * 32 + c0);
        const float2 R0 = *(const float2*)p;
        const float2 R1 = *(const float2*)(p + 512);
        const float2 G0 = *(const float2*)(p + 262144);
        const float2 G1 = *(const float2*)(p + 262656);
        const float2 B0 = *(const float2*)(p + 524288);
        const float2 B1 = *(const float2*)(p + 524800);
        const float OFF = (float)(128.0 / 255.0);
        // order: 0=w00, 1=w01, 2=w10, 3=w11
        const float rr[4] = {R0.x, R0.y, R1.x, R1.y};
        const float gg[4] = {G0.x, G0.y, G1.x, G1.y};
        const float bb[4] = {B0.x, B0.y, B1.x, B1.y};
        float yv[4], cbv[4], crv[4];
        #pragma unroll
        for (int k = 0; k < 4; ++k) {
            const float r_ = rr[k], g_ = gg[k], b_ = bb[k];
            const float y  = (float)(0.299) * r_ + (float)(0.587) * g_ + (float)(0.114) * b_;
            const float cb = (float)(-0.168735892) * r_ + (float)(-0.331264108) * g_ + 0.5f * b_;
            const float cr = 0.5f * r_ + (float)(-0.418687589) * g_ + (float)(-0.081312411) * b_;
            yv[k]  = clip01(y) - OFF;
            cbv[k] = clip01(cb + OFF);     // clipped, pre-subtract (subtract after pool)
            crv[k] = clip01(cr + OFF);
        }
        // transposed Y writes: column c holds Y[r][c] at YTT + c*36 + r
        *(float2*)&smem[YTT + c0 * 36 + r0]       = make_float2(yv[0], yv[2]);
        *(float2*)&smem[YTT + (c0 + 1) * 36 + r0] = make_float2(yv[1], yv[3]);
        // in-register pool, exact reference order ((w00+w01)+w10)+w11, then -OFF
        float sb = cbv[0];
        sb = sb + cbv[1];
        sb = sb + cbv[2];
        sb = sb + cbv[3];
        smem[CBT + qc * 20 + qr] = sb * 0.25f - OFF;
        float sr = crv[0];
        sr = sr + crv[1];
        sr = sr + crv[2];
        sr = sr + crv[3];
        smem[CRT + qc * 20 + qr] = sr * 0.25f - OFF;
    }
    __syncthreads();

    // ---- DCT + quantize: 8 threads per 8x8 block, one pass ----
    const int w  = t >> 6;           // wave 0..3
    const int l  = t & 63;
    const int bi = l >> 3;           // block-in-wave 0..5 (6,7 idle)
    const int lc = l & 7;            // stage-1 column / stage-2 row

    if (bi < 6) {
        const int sb = w * 6 + bi;   // block 0..23
        int xaddr, ch; size_t obase;
        if (sb < 16) {               // Y: 4x4 grid of 8x8 in the 32x32 tile
            const int sr = sb >> 2, sc = sb & 3;
            xaddr = YTT + (sc * 8 + lc) * 36 + sr * 8; ch = 0;
            obase = (((size_t)(b * 64 + th * 4 + sr)) * 64 + (tw * 4 + sc)) * 64;
        } else if (sb < 20) {        // Cb: 2x2 grid in pooled 16x16
            const int s = sb - 16, sr = s >> 1, sc = s & 1;
            xaddr = CBT + (sc * 8 + lc) * 20 + sr * 8; ch = 1;
            obase = (size_t)4194304 + (((size_t)(b * 32 + th * 2 + sr)) * 32 + (tw * 2 + sc)) * 64;
        } else {                     // Cr
            const int s = sb - 20, sr = s >> 1, sc = s & 1;
            xaddr = CRT + (sc * 8 + lc) * 20 + sr * 8; ch = 2;
            obase = (size_t)5242880 + (((size_t)(b * 32 + th * 2 + sr)) * 32 + (tw * 2 + sc)) * 64;
        }

        // stage 1: thread owns column lc; X column contiguous (transposed
        // layout) -> 2x ds_read_b128. T[i] = sum_j D[i][j] * X[j][lc].
        // Packed: rows (2p, 2p+1) share one v_pk_fma_f32 chain; each half's
        // op order is the same j-ascending fma chain as the bit-exact r9.
        float x[8];
        *(float4*)&x[0] = *(const float4*)&smem[xaddr];
        *(float4*)&x[4] = *(const float4*)&smem[xaddr + 4];
        const int tbase = TMP + w * 408 + bi * 68;   // 68-dword pad, 16B-aligned
        #pragma unroll
        for (int pp = 0; pp < 4; ++pp) {
            f32x2 acc = {0.0f, 0.0f};
            #pragma unroll
            for (int j = 0; j < 8; ++j) {
                const f32x2 d  = {Dm[2 * pp][j], Dm[2 * pp + 1][j]};
                const f32x2 xx = {x[j], x[j]};
                acc = __builtin_elementwise_fma(d, xx, acc);
            }
            smem[tbase + (2 * pp) * 8 + lc]     = acc.x;
            smem[tbase + (2 * pp + 1) * 8 + lc] = acc.y;
        }

        // stage 2: thread owns row lc of T (intra-wave RAW, no barrier —
        // bit-validated rounds 7-14). Packed over coefficient pairs.
        float tr[8], q[8];
        *(float4*)&tr[0] = *(const float4*)&smem[tbase + lc * 8];
        *(float4*)&tr[4] = *(const float4*)&smem[tbase + lc * 8 + 4];
        *(float4*)&q[0]  = *(const float4*)&smem[QNT + ch * 64 + lc * 8];
        *(float4*)&q[4]  = *(const float4*)&smem[QNT + ch * 64 + lc * 8 + 4];

        const float qadd = (float)(0.5 / 255.0);
        float o[8];
        #pragma unroll
        for (int pp = 0; pp < 4; ++pp) {
            f32x2 acc = {0.0f, 0.0f};
            #pragma unroll
            for (int k = 0; k < 8; ++k) {
                const f32x2 d  = {Dm[2 * pp][k], Dm[2 * pp + 1][k]};
                const f32x2 tt = {tr[k], tr[k]};
                acc = __builtin_elementwise_fma(tt, d, acc);   // fma(tr, Dm, s), k-ascending
            }
            // denominator: mul/add separately rounded (no FMA), matches numpy
            const float den0 = __fadd_rn(__fmul_rn(q[2 * pp], 2.5f), qadd);
            const float den1 = __fadd_rn(__fmul_rn(q[2 * pp + 1], 2.5f), qadd);
            o[2 * pp]     = rintf(acc.x / den0);  // IEEE div + round-half-even
            o[2 * pp + 1] = rintf(acc.y / den1);
        }
        float* op = out + obase + lc * 8;
        *(float4*)&op[0] = make_float4(o[0], o[1], o[2], o[3]);
        *(float4*)&op[4] = make_float4(o[4], o[5], o[6], o[7]);
    }
}

extern "C" void kernel_launch(void* const* d_in, const int* in_sizes, int n_in,
                              void* d_out, int out_size, void* d_ws, size_t ws_size,
                              hipStream_t stream) {
    const float* rgb   = (const float*)d_in[0];
    const float* quant = (const float*)d_in[1];
    float* out = (float*)d_out;
    dim3 grid(4096), block(256);
    hipLaunchKernelGGL(jpeg_kernel, grid, block, 0, stream, rgb, quant, out);
}